// Round 1
// baseline (533.343 us; speedup 1.0000x reference)
//
#include <hip/hip_runtime.h>
#include <math.h>

// Problem constants (fixed by the reference's setup_inputs)
#define CLS 2
#define BATCH 8
#define HH 512
#define WW 512
#define EPSV 1e-7f
#define INV_SCALE 0.125f

#define TCAP 256  // capacity for per-block compacted target list (N=160)

// ws layout: double gsum[4] = {sum_obj_c0, sum_obj_c1, sum_noobj_c0, sum_noobj_c1}
//            int    gcnt[4] = {n_obj_c0,  n_obj_c1,  n_noobj_c0,  n_noobj_c1}

__global__ __launch_bounds__(256) void heatmap_main(
    const float* __restrict__ predict, const float* __restrict__ targets,
    int nT, float* __restrict__ out, double* __restrict__ gsum,
    int* __restrict__ gcnt)
{
    __shared__ int s_cnt;
    __shared__ float s_cos[TCAP], s_sin[TCAP];
    __shared__ float s_x3[TCAP], s_x4[TCAP], s_y3[TCAP], s_y4[TCAP];
    __shared__ int   s_cid[TCAP];

    const int tid = threadIdx.x;
    const int blockPix = blockIdx.x * 256;
    const int b  = blockPix >> 18;            // / (H*W)
    const int i  = (blockPix >> 9) & (HH - 1); // row
    const int j0 = blockPix & (WW - 1);        // strip start (0 or 256)

    if (tid == 0) s_cnt = 0;
    __syncthreads();

    const float gy = (float)i + 0.5f;

    // --- per-block target compaction: batch filter + strip interval reject ---
    for (int t = tid; t < nT; t += 256) {
        const float* tp = targets + t * 7;
        const int tb = (int)tp[0];
        if (tb != b) continue;
        const float cx = tp[2] * INV_SCALE, cy = tp[3] * INV_SCALE;
        const float w_ = tp[4] * INV_SCALE, h_ = tp[5] * INV_SCALE;
        const float ang = tp[6];
        const float cs = cosf(ang), sn = sinf(ang);
        const float x = cx * cs + cy * sn;
        const float y = -cx * sn + cy * cs;
        const float x3 = x - 0.5f * h_, x4 = x + 0.5f * h_;
        const float y3 = y - 0.5f * w_, y4 = y + 0.5f * w_;

        // strip gx in [j0+0.5, j0+255.5], gy fixed -> exact vx/vy intervals
        const float gxl = (float)j0 + 0.5f, gxh = (float)j0 + 255.5f;
        const float a1 = cs * gxl + sn * gy, a2 = cs * gxh + sn * gy;
        const float vxlo = fminf(a1, a2), vxhi = fmaxf(a1, a2);
        const float b1 = -sn * gxl + cs * gy, b2 = -sn * gxh + cs * gy;
        const float vylo = fminf(b1, b2), vyhi = fmaxf(b1, b2);

        const float M = 0.51f; // outer box margin 0.5 + slack for fp rounding
        if (vxhi >= x3 - M && vxlo <= x4 + M && vyhi >= y3 - M && vylo <= y4 + M) {
            int slot = atomicAdd(&s_cnt, 1);
            s_cos[slot] = cs; s_sin[slot] = sn;
            s_x3[slot] = x3; s_x4[slot] = x4;
            s_y3[slot] = y3; s_y4[slot] = y4;
            s_cid[slot] = (int)tp[1];
        }
    }
    __syncthreads();
    const int cnt = s_cnt;

    // --- per-pixel mask evaluation ---
    const int j = j0 + tid;
    const float gx = (float)j + 0.5f;
    int objm = 0, outm = 0;
    for (int n = 0; n < cnt; ++n) {
        const float cs = s_cos[n], sn = s_sin[n];
        const float vx = cs * gx + sn * gy;
        const float vy = -sn * gx + cs * gy;
        const float x3 = s_x3[n], x4 = s_x4[n], y3 = s_y3[n], y4 = s_y4[n];
        const bool in_  = (x3 <= vx) & (vx <= x4) & (y3 <= vy) & (vy <= y4);
        const bool out_ = (x3 - 0.5f <= vx) & (vx <= x4 + 0.5f) &
                          (y3 - 0.5f <= vy) & (vy <= y4 + 0.5f);
        const int c = s_cid[n];
        objm |= ((int)in_) << c;
        outm |= ((int)out_) << c;
    }

    // --- sigmoid + heatmap ---
    const int base = (b * CLS * HH + i) * WW + j;
    const float p0 = predict[base];
    const float p1 = predict[base + HH * WW];
    const float conf0 = 1.0f / (1.0f + expf(-p0));
    const float conf1 = 1.0f / (1.0f + expf(-p1));
    out[1 + (b * HH + i) * WW + j] = fmaxf(conf0, conf1);

    // --- per-thread loss contributions ---
    float so0 = 0.f, so1 = 0.f, sn0 = 0.f, sn1 = 0.f;
    int co0 = 0, co1 = 0, cn0 = 0, cn1 = 0;
    {
        const float cc0 = fminf(fmaxf(conf0, EPSV), 1.0f - EPSV);
        const float cc1 = fminf(fmaxf(conf1, EPSV), 1.0f - EPSV);
        if (objm & 1) { so0 = logf(cc0); co0 = 1; }
        if (objm & 2) { so1 = logf(cc1); co1 = 1; }
        if (!(outm & 1)) { sn0 = logf(1.0f - cc0); cn0 = 1; }
        if (!(outm & 2)) { sn1 = logf(1.0f - cc1); cn1 = 1; }
    }

    // --- wave (64) shuffle reduction ---
    #pragma unroll
    for (int off = 32; off >= 1; off >>= 1) {
        so0 += __shfl_down(so0, off); so1 += __shfl_down(so1, off);
        sn0 += __shfl_down(sn0, off); sn1 += __shfl_down(sn1, off);
        co0 += __shfl_down(co0, off); co1 += __shfl_down(co1, off);
        cn0 += __shfl_down(cn0, off); cn1 += __shfl_down(cn1, off);
    }

    __shared__ float r_f[4][4];
    __shared__ int   r_i[4][4];
    const int wv = tid >> 6, ln = tid & 63;
    if (ln == 0) {
        r_f[wv][0] = so0; r_f[wv][1] = so1; r_f[wv][2] = sn0; r_f[wv][3] = sn1;
        r_i[wv][0] = co0; r_i[wv][1] = co1; r_i[wv][2] = cn0; r_i[wv][3] = cn1;
    }
    __syncthreads();
    if (tid == 0) {
        const float f0 = r_f[0][0] + r_f[1][0] + r_f[2][0] + r_f[3][0];
        const float f1 = r_f[0][1] + r_f[1][1] + r_f[2][1] + r_f[3][1];
        const float f2 = r_f[0][2] + r_f[1][2] + r_f[2][2] + r_f[3][2];
        const float f3 = r_f[0][3] + r_f[1][3] + r_f[2][3] + r_f[3][3];
        const int i0 = r_i[0][0] + r_i[1][0] + r_i[2][0] + r_i[3][0];
        const int i1 = r_i[0][1] + r_i[1][1] + r_i[2][1] + r_i[3][1];
        const int i2 = r_i[0][2] + r_i[1][2] + r_i[2][2] + r_i[3][2];
        const int i3 = r_i[0][3] + r_i[1][3] + r_i[2][3] + r_i[3][3];
        if (f0 != 0.f) atomicAdd(&gsum[0], (double)f0);
        if (f1 != 0.f) atomicAdd(&gsum[1], (double)f1);
        atomicAdd(&gsum[2], (double)f2);
        atomicAdd(&gsum[3], (double)f3);
        if (i0) atomicAdd(&gcnt[0], i0);
        if (i1) atomicAdd(&gcnt[1], i1);
        atomicAdd(&gcnt[2], i2);
        atomicAdd(&gcnt[3], i3);
    }
}

__global__ void heatmap_finalize(const double* __restrict__ gsum,
                                 const int* __restrict__ gcnt,
                                 float* __restrict__ out)
{
    if (threadIdx.x == 0 && blockIdx.x == 0) {
        float loss = 0.0f;
        #pragma unroll
        for (int c = 0; c < CLS; ++c) {
            const int no = gcnt[c];
            const int nn = gcnt[2 + c];
            if (no > 0) {
                const float lo = -(float)gsum[c]     / (float)(no > 1 ? no : 1);
                const float ln_ = -(float)gsum[2 + c] / (float)(nn > 1 ? nn : 1);
                loss += lo + ln_;  // NO_OBJ_SCALE = 1.0
            }
        }
        out[0] = loss;
    }
}

extern "C" void kernel_launch(void* const* d_in, const int* in_sizes, int n_in,
                              void* d_out, int out_size, void* d_ws, size_t ws_size,
                              hipStream_t stream) {
    const float* predict = (const float*)d_in[0];
    const float* targets = (const float*)d_in[1];
    const int nT = in_sizes[1] / 7;
    float* out = (float*)d_out;
    double* gsum = (double*)d_ws;
    int* gcnt = (int*)((char*)d_ws + 4 * sizeof(double));

    hipMemsetAsync(d_ws, 0, 4 * sizeof(double) + 4 * sizeof(int), stream);

    const int pixels = BATCH * HH * WW;
    heatmap_main<<<pixels / 256, 256, 0, stream>>>(predict, targets, nT, out,
                                                   gsum, gcnt);
    heatmap_finalize<<<1, 64, 0, stream>>>(gsum, gcnt, out);
}

// Round 2
// 94.927 us; speedup vs baseline: 5.6185x; 5.6185x over previous
//
#include <hip/hip_runtime.h>
#include <math.h>

// Problem constants (fixed by the reference's setup_inputs)
#define CLS 2
#define BATCH 8
#define HH 512
#define WW 512
#define EPSV 1e-7f
#define INV_SCALE 0.125f

#define TCAP 256   // capacity for per-block compacted target list (N=160)
#define NB 512     // atomic buckets per quantity (contention = 32768/512 = 64)

// ws layout: double gsum[4][NB]  (obj_c0, obj_c1, noobj_c0, noobj_c1)
//            int    gcnt[4][NB]

__global__ __launch_bounds__(256) void heatmap_main(
    const float* __restrict__ predict, const float* __restrict__ targets,
    int nT, float* __restrict__ out, double* __restrict__ gsum,
    int* __restrict__ gcnt)
{
    __shared__ int s_cnt;
    __shared__ float s_cos[TCAP], s_sin[TCAP];
    __shared__ float s_x3[TCAP], s_x4[TCAP], s_y3[TCAP], s_y4[TCAP];
    __shared__ int   s_cid[TCAP];

    const int tid = threadIdx.x;
    const int blockPix = blockIdx.x * 256;
    const int b  = blockPix >> 18;             // / (H*W)
    const int i  = (blockPix >> 9) & (HH - 1); // row
    const int j0 = blockPix & (WW - 1);        // strip start (0 or 256)

    if (tid == 0) s_cnt = 0;
    __syncthreads();

    const float gy = (float)i + 0.5f;

    // --- per-block target compaction: batch filter + strip interval reject ---
    for (int t = tid; t < nT; t += 256) {
        const float* tp = targets + t * 7;
        const int tb = (int)tp[0];
        if (tb != b) continue;
        const float cx = tp[2] * INV_SCALE, cy = tp[3] * INV_SCALE;
        const float w_ = tp[4] * INV_SCALE, h_ = tp[5] * INV_SCALE;
        const float ang = tp[6];
        const float cs = cosf(ang), sn = sinf(ang);
        const float x = cx * cs + cy * sn;
        const float y = -cx * sn + cy * cs;
        const float x3 = x - 0.5f * h_, x4 = x + 0.5f * h_;
        const float y3 = y - 0.5f * w_, y4 = y + 0.5f * w_;

        // strip gx in [j0+0.5, j0+255.5], gy fixed -> exact vx/vy intervals
        const float gxl = (float)j0 + 0.5f, gxh = (float)j0 + 255.5f;
        const float a1 = cs * gxl + sn * gy, a2 = cs * gxh + sn * gy;
        const float vxlo = fminf(a1, a2), vxhi = fmaxf(a1, a2);
        const float b1 = -sn * gxl + cs * gy, b2 = -sn * gxh + cs * gy;
        const float vylo = fminf(b1, b2), vyhi = fmaxf(b1, b2);

        const float M = 0.51f; // outer box margin 0.5 + slack for fp rounding
        if (vxhi >= x3 - M && vxlo <= x4 + M && vyhi >= y3 - M && vylo <= y4 + M) {
            int slot = atomicAdd(&s_cnt, 1);
            s_cos[slot] = cs; s_sin[slot] = sn;
            s_x3[slot] = x3; s_x4[slot] = x4;
            s_y3[slot] = y3; s_y4[slot] = y4;
            s_cid[slot] = (int)tp[1];
        }
    }
    __syncthreads();
    const int cnt = s_cnt;

    // --- per-pixel mask evaluation ---
    const int j = j0 + tid;
    const float gx = (float)j + 0.5f;
    int objm = 0, outm = 0;
    for (int n = 0; n < cnt; ++n) {
        const float cs = s_cos[n], sn = s_sin[n];
        const float vx = cs * gx + sn * gy;
        const float vy = -sn * gx + cs * gy;
        const float x3 = s_x3[n], x4 = s_x4[n], y3 = s_y3[n], y4 = s_y4[n];
        const bool in_  = (x3 <= vx) & (vx <= x4) & (y3 <= vy) & (vy <= y4);
        const bool out_ = (x3 - 0.5f <= vx) & (vx <= x4 + 0.5f) &
                          (y3 - 0.5f <= vy) & (vy <= y4 + 0.5f);
        const int c = s_cid[n];
        objm |= ((int)in_) << c;
        outm |= ((int)out_) << c;
    }

    // --- sigmoid + heatmap (fast hw intrinsics; tolerance is 6.4e-2) ---
    const int base = (b * CLS * HH + i) * WW + j;
    const float p0 = predict[base];
    const float p1 = predict[base + HH * WW];
    const float conf0 = __builtin_amdgcn_rcpf(1.0f + __expf(-p0));
    const float conf1 = __builtin_amdgcn_rcpf(1.0f + __expf(-p1));
    out[1 + (b * HH + i) * WW + j] = fmaxf(conf0, conf1);

    // --- per-thread loss contributions ---
    float so0 = 0.f, so1 = 0.f, sn0 = 0.f, sn1 = 0.f;
    int co0 = 0, co1 = 0, cn0 = 0, cn1 = 0;
    {
        const float cc0 = fminf(fmaxf(conf0, EPSV), 1.0f - EPSV);
        const float cc1 = fminf(fmaxf(conf1, EPSV), 1.0f - EPSV);
        if (objm & 1) { so0 = __logf(cc0); co0 = 1; }
        if (objm & 2) { so1 = __logf(cc1); co1 = 1; }
        if (!(outm & 1)) { sn0 = __logf(1.0f - cc0); cn0 = 1; }
        if (!(outm & 2)) { sn1 = __logf(1.0f - cc1); cn1 = 1; }
    }

    // --- wave (64) shuffle reduction ---
    #pragma unroll
    for (int off = 32; off >= 1; off >>= 1) {
        so0 += __shfl_down(so0, off); so1 += __shfl_down(so1, off);
        sn0 += __shfl_down(sn0, off); sn1 += __shfl_down(sn1, off);
        co0 += __shfl_down(co0, off); co1 += __shfl_down(co1, off);
        cn0 += __shfl_down(cn0, off); cn1 += __shfl_down(cn1, off);
    }

    __shared__ float r_f[4][4];
    __shared__ int   r_i[4][4];
    const int wv = tid >> 6, ln = tid & 63;
    if (ln == 0) {
        r_f[wv][0] = so0; r_f[wv][1] = so1; r_f[wv][2] = sn0; r_f[wv][3] = sn1;
        r_i[wv][0] = co0; r_i[wv][1] = co1; r_i[wv][2] = cn0; r_i[wv][3] = cn1;
    }
    __syncthreads();
    if (tid == 0) {
        const int bkt = blockIdx.x & (NB - 1);
        const float f0 = r_f[0][0] + r_f[1][0] + r_f[2][0] + r_f[3][0];
        const float f1 = r_f[0][1] + r_f[1][1] + r_f[2][1] + r_f[3][1];
        const float f2 = r_f[0][2] + r_f[1][2] + r_f[2][2] + r_f[3][2];
        const float f3 = r_f[0][3] + r_f[1][3] + r_f[2][3] + r_f[3][3];
        const int i0 = r_i[0][0] + r_i[1][0] + r_i[2][0] + r_i[3][0];
        const int i1 = r_i[0][1] + r_i[1][1] + r_i[2][1] + r_i[3][1];
        const int i2 = r_i[0][2] + r_i[1][2] + r_i[2][2] + r_i[3][2];
        const int i3 = r_i[0][3] + r_i[1][3] + r_i[2][3] + r_i[3][3];
        if (f0 != 0.f) atomicAdd(&gsum[0 * NB + bkt], (double)f0);
        if (f1 != 0.f) atomicAdd(&gsum[1 * NB + bkt], (double)f1);
        atomicAdd(&gsum[2 * NB + bkt], (double)f2);
        atomicAdd(&gsum[3 * NB + bkt], (double)f3);
        if (i0) atomicAdd(&gcnt[0 * NB + bkt], i0);
        if (i1) atomicAdd(&gcnt[1 * NB + bkt], i1);
        atomicAdd(&gcnt[2 * NB + bkt], i2);
        atomicAdd(&gcnt[3 * NB + bkt], i3);
    }
}

__global__ __launch_bounds__(512) void heatmap_finalize(
    const double* __restrict__ gsum, const int* __restrict__ gcnt,
    float* __restrict__ out)
{
    const int t = threadIdx.x;          // 0..511 == one bucket each
    double f[4]; int c[4];
    #pragma unroll
    for (int q = 0; q < 4; ++q) { f[q] = gsum[q * NB + t]; c[q] = gcnt[q * NB + t]; }

    #pragma unroll
    for (int off = 32; off >= 1; off >>= 1) {
        #pragma unroll
        for (int q = 0; q < 4; ++q) {
            f[q] += __shfl_down(f[q], off);
            c[q] += __shfl_down(c[q], off);
        }
    }

    __shared__ double sf[8][4];
    __shared__ int    si[8][4];
    const int wv = t >> 6, ln = t & 63;
    if (ln == 0) {
        #pragma unroll
        for (int q = 0; q < 4; ++q) { sf[wv][q] = f[q]; si[wv][q] = c[q]; }
    }
    __syncthreads();
    if (t == 0) {
        double F[4] = {0, 0, 0, 0}; int C[4] = {0, 0, 0, 0};
        for (int w = 0; w < 8; ++w)
            #pragma unroll
            for (int q = 0; q < 4; ++q) { F[q] += sf[w][q]; C[q] += si[w][q]; }
        float loss = 0.0f;
        #pragma unroll
        for (int cls = 0; cls < CLS; ++cls) {
            const int no = C[cls];
            const int nn = C[2 + cls];
            if (no > 0) {
                const float lo  = -(float)F[cls]     / (float)(no > 1 ? no : 1);
                const float ln_ = -(float)F[2 + cls] / (float)(nn > 1 ? nn : 1);
                loss += lo + ln_;  // NO_OBJ_SCALE = 1.0
            }
        }
        out[0] = loss;
    }
}

extern "C" void kernel_launch(void* const* d_in, const int* in_sizes, int n_in,
                              void* d_out, int out_size, void* d_ws, size_t ws_size,
                              hipStream_t stream) {
    const float* predict = (const float*)d_in[0];
    const float* targets = (const float*)d_in[1];
    const int nT = in_sizes[1] / 7;
    float* out = (float*)d_out;
    double* gsum = (double*)d_ws;
    int* gcnt = (int*)((char*)d_ws + 4 * NB * sizeof(double));

    hipMemsetAsync(d_ws, 0, 4 * NB * (sizeof(double) + sizeof(int)), stream);

    const int pixels = BATCH * HH * WW;
    heatmap_main<<<pixels / 256, 256, 0, stream>>>(predict, targets, nT, out,
                                                   gsum, gcnt);
    heatmap_finalize<<<1, 512, 0, stream>>>(gsum, gcnt, out);
}